// Round 6
// baseline (191.046 us; speedup 1.0000x reference)
//
#include <hip/hip_runtime.h>

#define THREADS 256
#define BLOCKS_PER_XCD 196
#define NBLOCKS (BLOCKS_PER_XCD * 8)   // 1568: all resident (6.1 blocks/CU)

// B=64, P=50000, H=W=512.
// XCD-pinned batch-major sweep: all 50176 threads of an XCD process batch b's
// 50000 points simultaneously (thread t <-> point t), then advance to b+1.
// Instantaneous image working set per XCD L2 = ~1 MB (fully resident) ->
// gather miss latency = L2-hit latency, maximizing MSHR-limited throughput.
// Indices prefetched 2 batches ahead; gathers issued 1 batch ahead.
__global__ __launch_bounds__(THREADS, 4) void rdc_kernel(
    const float* __restrict__ x,
    const int*   __restrict__ xA,
    const int*   __restrict__ yA,
    const int*   __restrict__ xB,
    const int*   __restrict__ yB,
    const float* __restrict__ gt,
    float* __restrict__ out,
    float inv_n)
{
    const int HW = 512 * 512;
    const int P  = 50000;

    // Physical mapping: consecutive block ids round-robin across the 8 XCDs.
    const int xcd = blockIdx.x & 7;
    const int lb  = blockIdx.x >> 3;                 // 0..195
    const int t   = lb * THREADS + threadIdx.x;      // 0..50175

    float acc = 0.0f;
    if (t < P) {
        const int b0 = xcd * 8;
        const float* __restrict__ img = x + (size_t)b0 * HW;
        const size_t pb = (size_t)b0 * P + t;

        // Pipeline state: indices for stages i, i+1; gathers for stage i.
        int   xa0, ya0, xb0, yb0;  float g0;   // stage i
        int   xa1, ya1, xb1, yb1;  float g1;   // stage i+1
        float zA0, zB0;                        // gather results for stage i

        // Prologue: idx[0], idx[1], gather[0].
        xa0 = __builtin_nontemporal_load(xA + pb);
        ya0 = __builtin_nontemporal_load(yA + pb);
        xb0 = __builtin_nontemporal_load(xB + pb);
        yb0 = __builtin_nontemporal_load(yB + pb);
        g0  = __builtin_nontemporal_load(gt + pb);
        xa1 = __builtin_nontemporal_load(xA + pb + P);
        ya1 = __builtin_nontemporal_load(yA + pb + P);
        xb1 = __builtin_nontemporal_load(xB + pb + P);
        yb1 = __builtin_nontemporal_load(yB + pb + P);
        g1  = __builtin_nontemporal_load(gt + pb + P);
        zA0 = img[(ya0 << 9) + xa0];
        zB0 = img[(yb0 << 9) + xb0];

        #pragma unroll
        for (int i = 0; i < 8; ++i) {
            // Issue idx[i+2] (keeps the stream pipe ahead of the gathers).
            int nxa = 0, nya = 0, nxb = 0, nyb = 0; float ng = 0.0f;
            if (i + 2 < 8) {
                const size_t p2 = pb + (size_t)(i + 2) * P;
                nxa = __builtin_nontemporal_load(xA + p2);
                nya = __builtin_nontemporal_load(yA + p2);
                nxb = __builtin_nontemporal_load(xB + p2);
                nyb = __builtin_nontemporal_load(yB + p2);
                ng  = __builtin_nontemporal_load(gt + p2);
            }
            // Issue gather[i+1] from the next image (idx ready 2 iters ago).
            float nzA = 0.0f, nzB = 0.0f;
            if (i + 1 < 8) {
                const float* __restrict__ img1 = img + HW;
                nzA = img1[(ya1 << 9) + xa1];
                nzB = img1[(yb1 << 9) + xb1];
            }
            // Compute stage i from already-in-flight gathers.
            const float d  = zA0 - zB0;
            const float tt = -g0 * d;
            // stable softplus: log1p(exp(t)) = max(t,0) + log1p(exp(-|t|))
            const float sp = fmaxf(tt, 0.0f) + log1pf(__expf(-fabsf(tt)));
            const float m  = fabsf(g0);          // 0 or 1
            acc += m * sp + (1.0f - m) * d * d;

            // Rotate pipeline.
            img += HW;
            xa0 = xa1; ya0 = ya1; xb0 = xb1; yb0 = yb1; g0 = g1;
            xa1 = nxa; ya1 = nya; xb1 = nxb; yb1 = nyb; g1 = ng;
            zA0 = nzA; zB0 = nzB;
        }
    }

    // wave64 reduce + block reduce + one atomic per block
    #pragma unroll
    for (int off = 32; off > 0; off >>= 1)
        acc += __shfl_down(acc, off, 64);

    __shared__ float wsum[THREADS / 64];
    const int lane = threadIdx.x & 63;
    const int wid  = threadIdx.x >> 6;
    if (lane == 0) wsum[wid] = acc;
    __syncthreads();
    if (threadIdx.x == 0) {
        float s = 0.0f;
        #pragma unroll
        for (int i2 = 0; i2 < THREADS / 64; ++i2) s += wsum[i2];
        atomicAdd(out, s * inv_n);
    }
}

extern "C" void kernel_launch(void* const* d_in, const int* in_sizes, int n_in,
                              void* d_out, int out_size, void* d_ws, size_t ws_size,
                              hipStream_t stream) {
    const float* x  = (const float*)d_in[0];
    const int*   xA = (const int*)d_in[1];
    const int*   yA = (const int*)d_in[2];
    const int*   xB = (const int*)d_in[3];
    const int*   yB = (const int*)d_in[4];
    const float* gt = (const float*)d_in[5];
    float* out = (float*)d_out;

    const int n = in_sizes[1];                 // B*P = 3,200,000
    const float inv_n = 1.0f / (float)n;

    hipMemsetAsync(out, 0, sizeof(float), stream);
    rdc_kernel<<<NBLOCKS, THREADS, 0, stream>>>(x, xA, yA, xB, yB, gt, out, inv_n);
}

// Round 8
// 176.727 us; speedup vs baseline: 1.0810x; 1.0810x over previous
//
#include <hip/hip_runtime.h>

#define THREADS 1024
#define PPT 13                    // ceil(12500 / 1024)
#define QPB 12500                 // points per block (quarter of a batch)
#define NBANDS 16
#define BAND_F 16384              // floats per band (32 rows x 512) = 64 KB

// B=64, P=50000, H=W=512.
// 256 blocks = 1/CU; block = (batch b, quarter ch). Points held in registers;
// the 1 MB image is swept through LDS in 16 double-buffered 64 KB bands:
//   issue global loads of band i+1 -> resolve band i (hides latency) ->
//   ds_write band i+1 -> sync.  Replaces per-lane random global gathers
// (MSHR-limited at ~0.2 lanes/cyc/CU) with LDS reads (no MSHR limit).
__global__ __launch_bounds__(THREADS) void rdc_kernel(
    const float* __restrict__ x,
    const int*   __restrict__ xA,
    const int*   __restrict__ yA,
    const int*   __restrict__ xB,
    const int*   __restrict__ yB,
    const float* __restrict__ gt,
    float* __restrict__ out,
    float inv_n)
{
    __shared__ float buf[2][BAND_F];          // 128 KB
    __shared__ float wsum[THREADS / 64];

    const int tid = threadIdx.x;
    // Physical mapping: consecutive block ids round-robin across 8 XCDs;
    // the 4 quarter-blocks of a batch land on the same XCD (shared L2 image).
    const int xcd = blockIdx.x & 7;
    const int w   = blockIdx.x >> 3;          // 0..31 within XCD
    const int bl  = w >> 2;                   // local batch 0..7
    const int ch  = w & 3;                    // quarter 0..3
    const int b   = xcd * 8 + bl;             // global batch

    const size_t pbase = (size_t)b * 50000 + ch * QPB;
    const float4* __restrict__ img4 = (const float4*)(x + (size_t)b * (512 * 512));

    // ---- Issue band-0 staging loads early (latency hides under point load).
    float4 st[4];
    #pragma unroll
    for (int j = 0; j < 4; ++j)
        st[j] = img4[j * THREADS + tid];

    // ---- Load this block's points into registers (coalesced, read-once).
    unsigned pa[PPT], pb[PPT];
    float g[PPT], zA[PPT], zB[PPT];
    #pragma unroll
    for (int k = 0; k < PPT; ++k) {
        const int s = k * THREADS + tid;
        if (s < QPB) {
            const size_t p = pbase + s;
            const int xa_ = __builtin_nontemporal_load(xA + p);
            const int ya_ = __builtin_nontemporal_load(yA + p);
            const int xb_ = __builtin_nontemporal_load(xB + p);
            const int yb_ = __builtin_nontemporal_load(yB + p);
            g[k]  = __builtin_nontemporal_load(gt + p);
            pa[k] = (unsigned)((ya_ << 9) | xa_);   // flat 18-bit offset
            pb[k] = (unsigned)((yb_ << 9) | xb_);
        } else {
            // Sentinel: band id 0x3FFFF never matches 0..15; g=0 -> loss 0.
            pa[k] = 0xFFFFFFFFu; pb[k] = 0xFFFFFFFFu; g[k] = 0.0f;
        }
        zA[k] = 0.0f; zB[k] = 0.0f;
    }

    // ---- Write band 0 and enter the band pipeline.
    {
        float4* d4 = (float4*)buf[0];
        #pragma unroll
        for (int j = 0; j < 4; ++j)
            d4[j * THREADS + tid] = st[j];
    }
    __syncthreads();

    for (int bi = 0; bi < NBANDS; ++bi) {
        // (1) Issue global loads of band bi+1 into registers (async wrt resolve).
        if (bi + 1 < NBANDS) {
            #pragma unroll
            for (int j = 0; j < 4; ++j)
                st[j] = img4[(bi + 1) * (BAND_F / 4) + j * THREADS + tid];
        }
        // (2) Resolve band bi from LDS — long phase, hides (1)'s latency.
        const float* lb = buf[bi & 1];
        #pragma unroll
        for (int k = 0; k < PPT; ++k) {
            if ((pa[k] >> 14) == (unsigned)bi) zA[k] = lb[pa[k] & 16383];
            if ((pb[k] >> 14) == (unsigned)bi) zB[k] = lb[pb[k] & 16383];
        }
        // (3) Write band bi+1 into the other buffer (safe: prev sync drained
        //     all reads of that buffer), then barrier for next iteration.
        if (bi + 1 < NBANDS) {
            float4* d4 = (float4*)buf[(bi + 1) & 1];
            #pragma unroll
            for (int j = 0; j < 4; ++j)
                d4[j * THREADS + tid] = st[j];
        }
        __syncthreads();
    }

    // ---- Loss from register-resident z values.
    float acc = 0.0f;
    #pragma unroll
    for (int k = 0; k < PPT; ++k) {
        const float d  = zA[k] - zB[k];
        const float t  = -g[k] * d;
        // stable softplus: log1p(exp(t)) = max(t,0) + log1p(exp(-|t|))
        const float sp = fmaxf(t, 0.0f) + log1pf(__expf(-fabsf(t)));
        const float m  = fabsf(g[k]);          // 0 or 1
        acc += m * sp + (1.0f - m) * d * d;    // sentinel slots contribute 0
    }

    // wave64 reduce + block reduce + one atomic per block
    #pragma unroll
    for (int off = 32; off > 0; off >>= 1)
        acc += __shfl_down(acc, off, 64);
    const int lane = tid & 63, wid = tid >> 6;
    if (lane == 0) wsum[wid] = acc;
    __syncthreads();
    if (tid == 0) {
        float s = 0.0f;
        #pragma unroll
        for (int i = 0; i < THREADS / 64; ++i) s += wsum[i];
        atomicAdd(out, s * inv_n);
    }
}

extern "C" void kernel_launch(void* const* d_in, const int* in_sizes, int n_in,
                              void* d_out, int out_size, void* d_ws, size_t ws_size,
                              hipStream_t stream) {
    const float* x  = (const float*)d_in[0];
    const int*   xA = (const int*)d_in[1];
    const int*   yA = (const int*)d_in[2];
    const int*   xB = (const int*)d_in[3];
    const int*   yB = (const int*)d_in[4];
    const float* gt = (const float*)d_in[5];
    float* out = (float*)d_out;

    const int n = in_sizes[1];                 // B*P = 3,200,000
    const float inv_n = 1.0f / (float)n;

    hipMemsetAsync(out, 0, sizeof(float), stream);
    rdc_kernel<<<256, THREADS, 0, stream>>>(x, xA, yA, xB, yB, gt, out, inv_n);
}